// Round 1
// baseline (691174.658 us; speedup 1.0000x reference)
//
#include <hip/hip_runtime.h>
#include <math.h>

#define SD   2048   // sequence steps
#define HD   1024   // hidden size
#define TPB  512    // threads per block (8 waves)
#define NBLK 256    // one block per CU -> co-resident

// ---- workspace layout (float offsets) ----
#define E_OFF     0              // exp(scores)            [2048]
#define CTXP_OFF  2048           // ctx partials 16 chunks [16*1024]
#define SUM_OFF   18432          // softmax denom          [16]
#define INP_OFF   18448          // combined input         [1024]
#define HH_OFF    19472          // w_hh@h + b_ih + b_hh   [2*4096]
#define H0_OFF    27664
#define C0_OFF    28688
#define H1_OFF    29712
#define C1_OFF    30736
#define X_OFF     31760
#define WS_FLOATS 32784
#define BAR_BYTE_OFF (WS_FLOATS * 4)

__device__ __forceinline__ float dot4(float4 a, float4 b) {
  return a.x * b.x + a.y * b.y + a.z * b.z + a.w * b.w;
}

__device__ __forceinline__ float wred(float v) {
  v += __shfl_xor(v, 32, 64);
  v += __shfl_xor(v, 16, 64);
  v += __shfl_xor(v, 8, 64);
  v += __shfl_xor(v, 4, 64);
  v += __shfl_xor(v, 2, 64);
  v += __shfl_xor(v, 1, 64);
  return v;
}

__device__ __forceinline__ float sigm(float x) { return 1.0f / (1.0f + __expf(-x)); }

// Two-level grid barrier: 8 group counters -> master -> generation flip.
// Agent-scope fences handle cross-XCD L2 non-coherence.
__device__ __forceinline__ void gridbar(unsigned* bar, int nblk) {
  __builtin_amdgcn_fence(__ATOMIC_RELEASE, "agent");
  __syncthreads();
  if (threadIdx.x == 0) {
    unsigned* master = bar;
    unsigned* gen    = bar + 16;
    unsigned* gcnt   = bar + 32 + (blockIdx.x & 7) * 16;
    const unsigned gsize = (unsigned)(nblk >> 3);
    unsigned g = __hip_atomic_load(gen, __ATOMIC_RELAXED, __HIP_MEMORY_SCOPE_AGENT);
    unsigned a = __hip_atomic_fetch_add(gcnt, 1u, __ATOMIC_ACQ_REL, __HIP_MEMORY_SCOPE_AGENT);
    if (a == gsize - 1u) {
      unsigned m = __hip_atomic_fetch_add(master, 1u, __ATOMIC_ACQ_REL, __HIP_MEMORY_SCOPE_AGENT);
      if (m == 7u) {
        __hip_atomic_store(master, 0u, __ATOMIC_RELAXED, __HIP_MEMORY_SCOPE_AGENT);
#pragma unroll
        for (int gg = 0; gg < 8; ++gg)
          __hip_atomic_store(bar + 32 + gg * 16, 0u, __ATOMIC_RELAXED, __HIP_MEMORY_SCOPE_AGENT);
        __hip_atomic_store(gen, g + 1u, __ATOMIC_RELEASE, __HIP_MEMORY_SCOPE_AGENT);
      } else {
        while (__hip_atomic_load(gen, __ATOMIC_ACQUIRE, __HIP_MEMORY_SCOPE_AGENT) == g)
          __builtin_amdgcn_s_sleep(1);
      }
    } else {
      while (__hip_atomic_load(gen, __ATOMIC_ACQUIRE, __HIP_MEMORY_SCOPE_AGENT) == g)
        __builtin_amdgcn_s_sleep(1);
    }
  }
  __syncthreads();
  __builtin_amdgcn_fence(__ATOMIC_ACQUIRE, "agent");
}

// scores row: e[r] = exp(attn_w[r,:1024]@x + attn_w[r,1024:]@h0 + attn_b[r])
__device__ __forceinline__ void score_row(int r, int lane, const float* __restrict__ attn_w,
                                          const float* __restrict__ attn_b, float* __restrict__ ws) {
  const float4* wr = (const float4*)(attn_w + (size_t)r * (2 * HD));
  const float4* xv = (const float4*)(ws + X_OFF);
  const float4* hv = (const float4*)(ws + H0_OFF);
  float acc = 0.f;
#pragma unroll
  for (int k = 0; k < 4; ++k) {
    const int idx = k * 64 + lane;
    acc += dot4(wr[idx], xv[idx]);
    acc += dot4(wr[256 + idx], hv[idx]);
  }
  acc = wred(acc);
  if (lane == 0) ws[E_OFF + r] = __expf(acc + attn_b[r]);
}

// hh[l][k + j*1024] = w_hh[l][rows k,k+1024,k+2048,k+3072] @ h[l] + b_ih + b_hh
__device__ __forceinline__ void hh_quad(int q, int lane, const float* __restrict__ w_hh,
                                        const float* __restrict__ b_ih, const float* __restrict__ b_hh,
                                        float* __restrict__ ws) {
  const int l = q >> 10, k = q & (HD - 1);
  const float* hv = ws + (l == 0 ? H0_OFF : H1_OFF);
  const float* wb = w_hh + (size_t)l * 4 * HD * HD;
  const float4* v  = (const float4*)hv;
  const float4* w0 = (const float4*)(wb + (size_t)k * HD);
  const float4* w1 = (const float4*)(wb + (size_t)(k + 1024) * HD);
  const float4* w2 = (const float4*)(wb + (size_t)(k + 2048) * HD);
  const float4* w3 = (const float4*)(wb + (size_t)(k + 3072) * HD);
  float a0 = 0.f, a1 = 0.f, a2 = 0.f, a3 = 0.f;
#pragma unroll
  for (int kk = 0; kk < 4; ++kk) {
    const int idx = kk * 64 + lane;
    float4 v4 = v[idx];
    a0 += dot4(w0[idx], v4);
    a1 += dot4(w1[idx], v4);
    a2 += dot4(w2[idx], v4);
    a3 += dot4(w3[idx], v4);
  }
  a0 = wred(a0); a1 = wred(a1); a2 = wred(a2); a3 = wred(a3);
  if (lane == 0) {
    const int bb = l * 4 * HD;
    ws[HH_OFF + bb + k]        = a0 + b_ih[bb + k]        + b_hh[bb + k];
    ws[HH_OFF + bb + k + 1024] = a1 + b_ih[bb + k + 1024] + b_hh[bb + k + 1024];
    ws[HH_OFF + bb + k + 2048] = a2 + b_ih[bb + k + 2048] + b_hh[bb + k + 2048];
    ws[HH_OFF + bb + k + 3072] = a3 + b_ih[bb + k + 3072] + b_hh[bb + k + 3072];
  }
}

// full LSTM cell for hidden index k of one layer (4 gate dots + pointwise)
__device__ __forceinline__ void lstm_quad(int k, int lane, const float* __restrict__ w,
                                          const float* __restrict__ hh, const float* __restrict__ vin,
                                          float* __restrict__ cst, float* __restrict__ hst,
                                          float* __restrict__ xout) {
  const float4* v  = (const float4*)vin;
  const float4* w0 = (const float4*)(w + (size_t)k * HD);
  const float4* w1 = (const float4*)(w + (size_t)(k + 1024) * HD);
  const float4* w2 = (const float4*)(w + (size_t)(k + 2048) * HD);
  const float4* w3 = (const float4*)(w + (size_t)(k + 3072) * HD);
  float a0 = 0.f, a1 = 0.f, a2 = 0.f, a3 = 0.f;
#pragma unroll
  for (int kk = 0; kk < 4; ++kk) {
    const int idx = kk * 64 + lane;
    float4 v4 = v[idx];
    a0 += dot4(w0[idx], v4);
    a1 += dot4(w1[idx], v4);
    a2 += dot4(w2[idx], v4);
    a3 += dot4(w3[idx], v4);
  }
  a0 = wred(a0); a1 = wred(a1); a2 = wred(a2); a3 = wred(a3);
  if (lane == 0) {
    float gi = a0 + hh[k];
    float gf = a1 + hh[k + 1024];
    float gg = a2 + hh[k + 2048];
    float go = a3 + hh[k + 3072];
    float c  = sigm(gf) * cst[k] + sigm(gi) * tanhf(gg);
    float h  = sigm(go) * tanhf(c);
    cst[k] = c;
    hst[k] = h;
    if (xout) xout[k] = h;
  }
}

// per-step classifier: probs[t] = softmax(lin2 @ relu(lin1 @ x + b1) + b2)
__device__ void classifier_block(const float* __restrict__ x, const float* __restrict__ lin1_w,
                                 const float* __restrict__ lin1_b, const float* __restrict__ lin2_w,
                                 const float* __restrict__ lin2_b, float* __restrict__ out2,
                                 float* lds) {
  const int tid = threadIdx.x, wid = tid >> 6, lane = tid & 63;
#pragma unroll
  for (int oi = 0; oi < 8; ++oi) {
    const int o = wid * 8 + oi;
    const float4* wr = (const float4*)(lin1_w + (size_t)o * HD);
    float acc = 0.f;
#pragma unroll
    for (int k = 0; k < 4; ++k) {
      const int idx = k * 64 + lane;
      float4 w4 = wr[idx];
      float4 v4 = *(const float4*)(x + idx * 4);
      acc += dot4(w4, v4);
    }
    acc = wred(acc);
    if (lane == 0) lds[o] = fmaxf(acc + lin1_b[o], 0.f);
  }
  __syncthreads();
  if (tid == 0) {
    float l0 = lin2_b[0], l1 = lin2_b[1];
#pragma unroll
    for (int j = 0; j < 64; ++j) {
      l0 += lin2_w[j] * lds[j];
      l1 += lin2_w[64 + j] * lds[j];
    }
    float m  = fmaxf(l0, l1);
    float e0 = __expf(l0 - m), e1 = __expf(l1 - m);
    float inv = 1.f / (e0 + e1);
    out2[0] = e0 * inv;
    out2[1] = e1 * inv;
  }
  __syncthreads();
}

__global__ void __launch_bounds__(TPB, 2)
decoder_kernel(const float* __restrict__ enc, const float* __restrict__ attn_w,
               const float* __restrict__ attn_b, const float* __restrict__ comb_w,
               const float* __restrict__ comb_b, const float* __restrict__ w_ih,
               const float* __restrict__ w_hh, const float* __restrict__ b_ih,
               const float* __restrict__ b_hh, const float* __restrict__ lin1_w,
               const float* __restrict__ lin1_b, const float* __restrict__ lin2_w,
               const float* __restrict__ lin2_b, const float* __restrict__ hidden,
               const float* __restrict__ cell, float* __restrict__ out,
               float* __restrict__ ws, unsigned* __restrict__ bar) {
  __shared__ __align__(16) float lds[HD];
  const int tid  = threadIdx.x;
  const int wid  = tid >> 6, lane = tid & 63;
  const int bid  = blockIdx.x, nblk = gridDim.x;
  const int gw   = bid * 8 + wid;

  // init recurrent state
  if (bid == 0) {
    for (int i = tid; i < HD; i += TPB) {
      ws[H0_OFF + i] = hidden[i];
      ws[H1_OFF + i] = hidden[HD + i];
      ws[C0_OFF + i] = cell[i];
      ws[C1_OFF + i] = cell[HD + i];
      ws[X_OFF + i]  = 0.f;
    }
  }
  gridbar(bar, nblk);

  for (int t = 0; t < SD; ++t) {
    // ---- Phase A: scores + w_hh@h precompute; last block: classifier for t-1 ----
    if (bid < nblk - 1) {
      for (int task = gw; task < 4096; task += (nblk - 1) * 8) {
        if (task < 2048) score_row(task, lane, attn_w, attn_b, ws);
        else             hh_quad(task - 2048, lane, w_hh, b_ih, b_hh, ws);
      }
    } else if (t > 0) {
      classifier_block(ws + X_OFF, lin1_w, lin1_b, lin2_w, lin2_b,
                       out + (size_t)(t - 1) * 2, lds);
    }
    gridbar(bar, nblk);

    // ---- Phase B: ctx partials (16 i-chunks x 16 h-groups) + softmax denom ----
    {
      const int chunk = bid >> 4, hg = bid & 15;
      const int i0 = chunk * 128 + wid * 16;
      const int hb = hg * 64 + lane;
      float a = 0.f;
#pragma unroll
      for (int i = 0; i < 16; ++i)
        a += ws[E_OFF + i0 + i] * enc[(size_t)(i0 + i) * HD + hb];
      lds[wid * 64 + lane] = a;
      __syncthreads();
      if (wid == 0) {
        float s = 0.f;
#pragma unroll
        for (int w2 = 0; w2 < 8; ++w2) s += lds[w2 * 64 + lane];
        ws[CTXP_OFF + chunk * HD + hb] = s;
      } else if (wid == 1 && bid == 0) {
        float s = 0.f;
        for (int i = lane; i < SD; i += 64) s += ws[E_OFF + i];
        s = wred(s);
        if (lane == 0) ws[SUM_OFF] = s;
      }
    }
    gridbar(bar, nblk);

    // ---- Phase C: reduce ctx into LDS, then inp = relu(comb_w @ [x, ctx] + b) ----
    {
      const float invs = 1.f / ws[SUM_OFF];
      for (int h4 = tid; h4 < HD / 4; h4 += TPB) {
        float sx = 0, sy = 0, sz = 0, sw = 0;
#pragma unroll
        for (int ch = 0; ch < 16; ++ch) {
          float4 p = *(const float4*)(ws + CTXP_OFF + ch * HD + h4 * 4);
          sx += p.x; sy += p.y; sz += p.z; sw += p.w;
        }
        float4 r;
        r.x = sx * invs; r.y = sy * invs; r.z = sz * invs; r.w = sw * invs;
        *(float4*)(&lds[h4 * 4]) = r;
      }
      __syncthreads();
      if (wid < 4) {
        const int j = bid * 4 + wid;
        const float4* wr = (const float4*)(comb_w + (size_t)j * (2 * HD));
        const float4* xv = (const float4*)(ws + X_OFF);
        float acc = 0.f;
#pragma unroll
        for (int k = 0; k < 4; ++k) {
          const int idx = k * 64 + lane;
          acc += dot4(wr[idx], xv[idx]);
          float4 c4 = *(const float4*)(&lds[idx * 4]);
          acc += dot4(wr[256 + idx], c4);
        }
        acc = wred(acc);
        if (lane == 0) ws[INP_OFF + j] = fmaxf(acc + comb_b[j], 0.f);
      }
    }
    gridbar(bar, nblk);

    // ---- Phase D: LSTM layer 0 ----
    if (wid < 4)
      lstm_quad(bid * 4 + wid, lane, w_ih, ws + HH_OFF, ws + INP_OFF,
                ws + C0_OFF, ws + H0_OFF, nullptr);
    gridbar(bar, nblk);

    // ---- Phase E: LSTM layer 1 (writes h1 and x for next step) ----
    if (wid < 4)
      lstm_quad(bid * 4 + wid, lane, w_ih + (size_t)4 * HD * HD, ws + HH_OFF + 4 * HD,
                ws + H0_OFF, ws + C1_OFF, ws + H1_OFF, ws + X_OFF);
    gridbar(bar, nblk);
  }

  // ---- epilogue: final states + last-step classifier ----
  if (bid == 0) {
    for (int i = tid; i < HD; i += TPB) {
      out[4096 + i]           = ws[H0_OFF + i];
      out[4096 + HD + i]      = ws[H1_OFF + i];
      out[4096 + 2 * HD + i]  = ws[C0_OFF + i];
      out[4096 + 3 * HD + i]  = ws[C1_OFF + i];
    }
  } else if (bid == nblk - 1) {
    classifier_block(ws + X_OFF, lin1_w, lin1_b, lin2_w, lin2_b,
                     out + (size_t)(SD - 1) * 2, lds);
  }
}

extern "C" void kernel_launch(void* const* d_in, const int* in_sizes, int n_in,
                              void* d_out, int out_size, void* d_ws, size_t ws_size,
                              hipStream_t stream) {
  const float* enc    = (const float*)d_in[0];
  const float* hidden = (const float*)d_in[1];
  const float* cell   = (const float*)d_in[2];
  const float* attn_w = (const float*)d_in[3];
  const float* attn_b = (const float*)d_in[4];
  const float* comb_w = (const float*)d_in[5];
  const float* comb_b = (const float*)d_in[6];
  const float* w_ih   = (const float*)d_in[7];
  const float* w_hh   = (const float*)d_in[8];
  const float* b_ih   = (const float*)d_in[9];
  const float* b_hh   = (const float*)d_in[10];
  const float* lin1_w = (const float*)d_in[11];
  const float* lin1_b = (const float*)d_in[12];
  const float* lin2_w = (const float*)d_in[13];
  const float* lin2_b = (const float*)d_in[14];
  float* out = (float*)d_out;
  float* ws  = (float*)d_ws;
  unsigned* bar = (unsigned*)((char*)d_ws + BAR_BYTE_OFF);

  hipMemsetAsync(bar, 0, 1024, stream);
  decoder_kernel<<<dim3(NBLK), dim3(TPB), 0, stream>>>(
      enc, attn_w, attn_b, comb_w, comb_b, w_ih, w_hh, b_ih, b_hh,
      lin1_w, lin1_b, lin2_w, lin2_b, hidden, cell, out, ws, bar);
  (void)in_sizes; (void)n_in; (void)out_size; (void)ws_size;
}

// Round 2
// 93140.393 us; speedup vs baseline: 7.4208x; 7.4208x over previous
//
#include <hip/hip_runtime.h>
#include <math.h>

#define SD   2048   // sequence steps
#define HD   1024   // hidden size
#define TPB  512    // threads per block (8 waves)
#define NBLK 256    // one block per CU -> co-resident

// ---- workspace layout (float offsets) ----
#define E_OFF     0                      // exp(scores)            [2048]
#define CTXP_OFF  2048                   // ctx partials 16 chunks [16*1024]
#define SUM_OFF   (CTXP_OFF + 16 * HD)   // softmax denom
#define INP_OFF   (SUM_OFF + 16)         // combined input         [1024]
#define HH_OFF    (INP_OFF + HD)         // w_hh@h + b_ih + b_hh   [2*4096]
#define H0_OFF    (HH_OFF + 8192)
#define X_OFF     (H0_OFF + HD)          // x == h1 (merged)
#define WS_FLOATS (X_OFF + HD)
#define BAR_BYTE_OFF ((((WS_FLOATS) * 4) + 255) & ~255)

typedef unsigned long long u64;

// ---- coherent (LLC-level) scalar/64b accessors: bypass L1/L2, no fences ----
__device__ __forceinline__ float ldcf(const float* p) {
  return __hip_atomic_load(p, __ATOMIC_RELAXED, __HIP_MEMORY_SCOPE_AGENT);
}
__device__ __forceinline__ float2 ldc2(const float* p) {
  u64 u = __hip_atomic_load((const u64*)p, __ATOMIC_RELAXED, __HIP_MEMORY_SCOPE_AGENT);
  union { u64 u; float2 f; } c; c.u = u; return c.f;
}
__device__ __forceinline__ void stcf(float* p, float v) {
  __hip_atomic_store(p, v, __ATOMIC_RELAXED, __HIP_MEMORY_SCOPE_AGENT);
}

__device__ __forceinline__ float dot4(float4 a, float4 b) {
  return a.x * b.x + a.y * b.y + a.z * b.z + a.w * b.w;
}

__device__ __forceinline__ float wred(float v) {
  v += __shfl_xor(v, 32, 64);
  v += __shfl_xor(v, 16, 64);
  v += __shfl_xor(v, 8, 64);
  v += __shfl_xor(v, 4, 64);
  v += __shfl_xor(v, 2, 64);
  v += __shfl_xor(v, 1, 64);
  return v;
}

__device__ __forceinline__ float sigm(float x) { return 1.0f / (1.0f + __expf(-x)); }

// Fence-free monotonic-epoch grid barrier.
// bar[0]=master, bar[32+g*16]=group counters, bar[160+g*16]=gen replicas.
// Correctness: producers publish via stcf (sc1 write-through); the compiler
// drains vmcnt at the __syncthreads before arrival, so data is at the
// coherence point before the arrival RMW. Consumers read via ldcf/ldc2
// (sc1 loads), so no invalidation is ever needed -> L2 keeps the weights.
__device__ __forceinline__ void gridbar(unsigned* bar, unsigned ep) {
  __syncthreads();
  if (threadIdx.x == 0) {
    const int g = blockIdx.x & 7;
    unsigned a = __hip_atomic_fetch_add(bar + 32 + g * 16, 1u,
                                        __ATOMIC_RELAXED, __HIP_MEMORY_SCOPE_AGENT);
    if (a == ep * 32u - 1u) {
      unsigned m = __hip_atomic_fetch_add(bar, 1u,
                                          __ATOMIC_RELAXED, __HIP_MEMORY_SCOPE_AGENT);
      if (m == ep * 8u - 1u) {
#pragma unroll
        for (int gg = 0; gg < 8; ++gg)
          __hip_atomic_store(bar + 160 + gg * 16, ep,
                             __ATOMIC_RELAXED, __HIP_MEMORY_SCOPE_AGENT);
      } else {
        while (__hip_atomic_load(bar + 160 + g * 16,
                                 __ATOMIC_RELAXED, __HIP_MEMORY_SCOPE_AGENT) < ep)
          __builtin_amdgcn_s_sleep(2);
      }
    } else {
      while (__hip_atomic_load(bar + 160 + g * 16,
                               __ATOMIC_RELAXED, __HIP_MEMORY_SCOPE_AGENT) < ep)
        __builtin_amdgcn_s_sleep(2);
    }
  }
  __syncthreads();
}

// e[r] = exp(attn_w[r,:1024]@x + attn_w[r,1024:]@h0 + attn_b[r])
__device__ __forceinline__ void score_row(int r, int lane,
                                          const float* __restrict__ attn_w,
                                          const float* __restrict__ attn_b,
                                          const float* lds_x, const float* lds_h0,
                                          float* ws) {
  const float4* wr = (const float4*)(attn_w + (size_t)r * (2 * HD));
  const float4* xv = (const float4*)lds_x;
  const float4* hv = (const float4*)lds_h0;
  float acc = 0.f;
#pragma unroll
  for (int k = 0; k < 4; ++k) {
    const int idx = k * 64 + lane;
    acc += dot4(wr[idx], xv[idx]);
    acc += dot4(wr[256 + idx], hv[idx]);
  }
  acc = wred(acc);
  if (lane == 0) stcf(ws + E_OFF + r, __expf(acc + attn_b[r]));
}

// hh[l][k + j*1024] = w_hh[l][rows k + j*1024] @ h[l] + b_ih + b_hh
__device__ __forceinline__ void hh_quad(int q, int lane, const float* __restrict__ w_hh,
                                        const float* __restrict__ b_ih,
                                        const float* __restrict__ b_hh,
                                        const float* lds_x, const float* lds_h0,
                                        float* ws) {
  const int l = q >> 10, k = q & (HD - 1);
  const float4* v  = (const float4*)(l == 0 ? lds_h0 : lds_x);  // h1 == x
  const float* wb = w_hh + (size_t)l * 4 * HD * HD;
  const float4* w0 = (const float4*)(wb + (size_t)k * HD);
  const float4* w1 = (const float4*)(wb + (size_t)(k + 1024) * HD);
  const float4* w2 = (const float4*)(wb + (size_t)(k + 2048) * HD);
  const float4* w3 = (const float4*)(wb + (size_t)(k + 3072) * HD);
  float a0 = 0.f, a1 = 0.f, a2 = 0.f, a3 = 0.f;
#pragma unroll
  for (int kk = 0; kk < 4; ++kk) {
    const int idx = kk * 64 + lane;
    float4 v4 = v[idx];
    a0 += dot4(w0[idx], v4);
    a1 += dot4(w1[idx], v4);
    a2 += dot4(w2[idx], v4);
    a3 += dot4(w3[idx], v4);
  }
  a0 = wred(a0); a1 = wred(a1); a2 = wred(a2); a3 = wred(a3);
  if (lane == 0) {
    const int bb = l * 4 * HD;
    stcf(ws + HH_OFF + bb + k,        a0 + b_ih[bb + k]        + b_hh[bb + k]);
    stcf(ws + HH_OFF + bb + k + 1024, a1 + b_ih[bb + k + 1024] + b_hh[bb + k + 1024]);
    stcf(ws + HH_OFF + bb + k + 2048, a2 + b_ih[bb + k + 2048] + b_hh[bb + k + 2048]);
    stcf(ws + HH_OFF + bb + k + 3072, a3 + b_ih[bb + k + 3072] + b_hh[bb + k + 3072]);
  }
}

// LSTM cell for hidden index k of one layer; c lives in lane-0 register
__device__ __forceinline__ void lstm_quad(int k, int lane, const float* __restrict__ w,
                                          const float* hhp, const float* lds_v,
                                          float& c, float* hout_ws) {
  // prefetch hh early (all lanes, same addr -> single LLC line req each)
  float hh0 = ldcf(hhp + k);
  float hh1 = ldcf(hhp + k + 1024);
  float hh2 = ldcf(hhp + k + 2048);
  float hh3 = ldcf(hhp + k + 3072);
  const float4* v  = (const float4*)lds_v;
  const float4* w0 = (const float4*)(w + (size_t)k * HD);
  const float4* w1 = (const float4*)(w + (size_t)(k + 1024) * HD);
  const float4* w2 = (const float4*)(w + (size_t)(k + 2048) * HD);
  const float4* w3 = (const float4*)(w + (size_t)(k + 3072) * HD);
  float a0 = 0.f, a1 = 0.f, a2 = 0.f, a3 = 0.f;
#pragma unroll
  for (int kk = 0; kk < 4; ++kk) {
    const int idx = kk * 64 + lane;
    float4 v4 = v[idx];
    a0 += dot4(w0[idx], v4);
    a1 += dot4(w1[idx], v4);
    a2 += dot4(w2[idx], v4);
    a3 += dot4(w3[idx], v4);
  }
  a0 = wred(a0); a1 = wred(a1); a2 = wred(a2); a3 = wred(a3);
  if (lane == 0) {
    float gi = a0 + hh0, gf = a1 + hh1, gg = a2 + hh2, go = a3 + hh3;
    c = sigm(gf) * c + sigm(gi) * tanhf(gg);
    stcf(hout_ws + k, sigm(go) * tanhf(c));
  }
}

// probs[t] = softmax(lin2 @ relu(lin1 @ x + b1) + b2); x from LDS
__device__ void classifier_block(const float* lds_x, const float* __restrict__ lin1_w,
                                 const float* __restrict__ lin1_b,
                                 const float* __restrict__ lin2_w,
                                 const float* __restrict__ lin2_b,
                                 float* __restrict__ out2, float* lds_red) {
  const int tid = threadIdx.x, wid = tid >> 6, lane = tid & 63;
  const float4* xv = (const float4*)lds_x;
#pragma unroll
  for (int oi = 0; oi < 8; ++oi) {
    const int o = wid * 8 + oi;
    const float4* wr = (const float4*)(lin1_w + (size_t)o * HD);
    float acc = 0.f;
#pragma unroll
    for (int k = 0; k < 4; ++k) {
      const int idx = k * 64 + lane;
      acc += dot4(wr[idx], xv[idx]);
    }
    acc = wred(acc);
    if (lane == 0) lds_red[o] = fmaxf(acc + lin1_b[o], 0.f);
  }
  __syncthreads();
  if (tid == 0) {
    float l0 = lin2_b[0], l1 = lin2_b[1];
#pragma unroll
    for (int j = 0; j < 64; ++j) {
      l0 += lin2_w[j] * lds_red[j];
      l1 += lin2_w[64 + j] * lds_red[j];
    }
    float m  = fmaxf(l0, l1);
    float e0 = __expf(l0 - m), e1 = __expf(l1 - m);
    float inv = 1.f / (e0 + e1);
    out2[0] = e0 * inv;
    out2[1] = e1 * inv;
  }
  __syncthreads();
}

__global__ void __launch_bounds__(TPB, 2)
decoder_kernel(const float* __restrict__ enc, const float* __restrict__ attn_w,
               const float* __restrict__ attn_b, const float* __restrict__ comb_w,
               const float* __restrict__ comb_b, const float* __restrict__ w_ih,
               const float* __restrict__ w_hh, const float* __restrict__ b_ih,
               const float* __restrict__ b_hh, const float* __restrict__ lin1_w,
               const float* __restrict__ lin1_b, const float* __restrict__ lin2_w,
               const float* __restrict__ lin2_b, const float* __restrict__ hidden,
               const float* __restrict__ cell, float* __restrict__ out,
               float* __restrict__ ws, unsigned* __restrict__ bar) {
  __shared__ __align__(16) float lds_x[HD];
  __shared__ __align__(16) float lds_h0[HD];
  __shared__ __align__(16) float lds_ctx[HD];   // ctx in phase C, inp in phase D
  __shared__ __align__(16) float lds_red[TPB];
  const int tid = threadIdx.x;
  const int wid = tid >> 6, lane = tid & 63;
  const int bid = blockIdx.x;
  const int gw  = bid * 8 + wid;
  const int k4  = bid * 4 + wid;   // this wave's hidden index in phases C/D/E
  unsigned ep = 0;

  // cell state lives in lane-0 registers (never crosses blocks)
  float c0 = 0.f, c1 = 0.f;
  if (wid < 4 && lane == 0) { c0 = cell[k4]; c1 = cell[HD + k4]; }

  // init shared recurrent state (coherent publish). x0 == 0 == h1_init here.
  if (bid == 0) {
    for (int i = tid; i < HD; i += TPB) {
      stcf(ws + H0_OFF + i, hidden[i]);
      stcf(ws + X_OFF + i, 0.f);
    }
  }
  gridbar(bar, ++ep);

  for (int t = 0; t < SD; ++t) {
    // ---- Phase A: stage x|h0, scores + w_hh@h precompute; blk255 also classifier ----
    {
      float2 xv = ldc2(ws + X_OFF + tid * 2);
      float2 hv = ldc2(ws + H0_OFF + tid * 2);
      *(float2*)&lds_x[tid * 2]  = xv;
      *(float2*)&lds_h0[tid * 2] = hv;
      __syncthreads();
      if (bid == NBLK - 1 && t > 0)
        classifier_block(lds_x, lin1_w, lin1_b, lin2_w, lin2_b,
                         out + (size_t)(t - 1) * 2, lds_red);
      for (int task = gw; task < 4096; task += 2048) {
        if (task < 2048) score_row(task, lane, attn_w, attn_b, lds_x, lds_h0, ws);
        else             hh_quad(task - 2048, lane, w_hh, b_ih, b_hh, lds_x, lds_h0, ws);
      }
    }
    gridbar(bar, ++ep);

    // ---- Phase B: ctx partials (16 i-chunks x 16 h-groups) + softmax denom ----
    {
      const int chunk = bid >> 4, hg = bid & 15;
      const int i0 = chunk * 128 + wid * 16;
      const int hb = hg * 64 + lane;
      float ev = (lane < 16) ? ldcf(ws + E_OFF + i0 + lane) : 0.f;
      float a = 0.f;
#pragma unroll
      for (int i = 0; i < 16; ++i) {
        float ei = __shfl(ev, i, 64);
        a += ei * enc[(size_t)(i0 + i) * HD + hb];
      }
      lds_red[wid * 64 + lane] = a;
      __syncthreads();
      if (wid == 0) {
        float s = 0.f;
#pragma unroll
        for (int w2 = 0; w2 < 8; ++w2) s += lds_red[w2 * 64 + lane];
        stcf(ws + CTXP_OFF + chunk * HD + hb, s);
      } else if (wid == 1 && bid == 0) {
        float s = 0.f;
#pragma unroll
        for (int j = 0; j < 16; ++j) {
          float2 e2 = ldc2(ws + E_OFF + j * 128 + lane * 2);
          s += e2.x + e2.y;
        }
        s = wred(s);
        if (lane == 0) stcf(ws + SUM_OFF, s);
      }
    }
    gridbar(bar, ++ep);

    // ---- Phase C: reduce ctx partials -> LDS; inp = relu(comb_w @ [x, ctx] + b) ----
    {
      const float invs = 1.f / ldcf(ws + SUM_OFF);
      float sx = 0.f, sy = 0.f;
#pragma unroll
      for (int ch = 0; ch < 16; ++ch) {
        float2 p = ldc2(ws + CTXP_OFF + ch * HD + tid * 2);
        sx += p.x; sy += p.y;
      }
      float2 r; r.x = sx * invs; r.y = sy * invs;
      *(float2*)&lds_ctx[tid * 2] = r;
      __syncthreads();
      if (wid < 4) {
        const float4* wr = (const float4*)(comb_w + (size_t)k4 * (2 * HD));
        const float4* xv = (const float4*)lds_x;
        const float4* cv = (const float4*)lds_ctx;
        float acc = 0.f;
#pragma unroll
        for (int k = 0; k < 4; ++k) {
          const int idx = k * 64 + lane;
          acc += dot4(wr[idx], xv[idx]);
          acc += dot4(wr[256 + idx], cv[idx]);
        }
        acc = wred(acc);
        if (lane == 0) stcf(ws + INP_OFF + k4, fmaxf(acc + comb_b[k4], 0.f));
      }
    }
    gridbar(bar, ++ep);

    // ---- Phase D: LSTM layer 0 ----
    {
      float2 iv = ldc2(ws + INP_OFF + tid * 2);
      *(float2*)&lds_ctx[tid * 2] = iv;   // reuse as inp
      __syncthreads();
      if (wid < 4)
        lstm_quad(k4, lane, w_ih, ws + HH_OFF, lds_ctx, c0, ws + H0_OFF);
    }
    gridbar(bar, ++ep);

    // ---- Phase E: LSTM layer 1 (writes x == h1) ----
    {
      float2 hv = ldc2(ws + H0_OFF + tid * 2);
      *(float2*)&lds_h0[tid * 2] = hv;
      __syncthreads();
      if (wid < 4)
        lstm_quad(k4, lane, w_ih + (size_t)4 * HD * HD, ws + HH_OFF + 4 * HD,
                  lds_h0, c1, ws + X_OFF);
    }
    gridbar(bar, ++ep);
  }

  // ---- epilogue: final classifier + states ----
  if (bid == NBLK - 1) {
    float2 xv = ldc2(ws + X_OFF + tid * 2);
    *(float2*)&lds_x[tid * 2] = xv;
    __syncthreads();
    classifier_block(lds_x, lin1_w, lin1_b, lin2_w, lin2_b,
                     out + (size_t)(SD - 1) * 2, lds_red);
  }
  if (wid < 4 && lane == 0) {
    out[4096 + 2 * HD + k4] = c0;
    out[4096 + 3 * HD + k4] = c1;
  }
  if (bid == 0) {
    for (int i = tid; i < HD; i += TPB) {
      out[4096 + i]      = ldcf(ws + H0_OFF + i);
      out[4096 + HD + i] = ldcf(ws + X_OFF + i);
    }
  }
}

extern "C" void kernel_launch(void* const* d_in, const int* in_sizes, int n_in,
                              void* d_out, int out_size, void* d_ws, size_t ws_size,
                              hipStream_t stream) {
  const float* enc    = (const float*)d_in[0];
  const float* hidden = (const float*)d_in[1];
  const float* cell   = (const float*)d_in[2];
  const float* attn_w = (const float*)d_in[3];
  const float* attn_b = (const float*)d_in[4];
  const float* comb_w = (const float*)d_in[5];
  const float* comb_b = (const float*)d_in[6];
  const float* w_ih   = (const float*)d_in[7];
  const float* w_hh   = (const float*)d_in[8];
  const float* b_ih   = (const float*)d_in[9];
  const float* b_hh   = (const float*)d_in[10];
  const float* lin1_w = (const float*)d_in[11];
  const float* lin1_b = (const float*)d_in[12];
  const float* lin2_w = (const float*)d_in[13];
  const float* lin2_b = (const float*)d_in[14];
  float* out = (float*)d_out;
  float* ws  = (float*)d_ws;
  unsigned* bar = (unsigned*)((char*)d_ws + BAR_BYTE_OFF);

  hipMemsetAsync(bar, 0, 4096, stream);
  decoder_kernel<<<dim3(NBLK), dim3(TPB), 0, stream>>>(
      enc, attn_w, attn_b, comb_w, comb_b, w_ih, w_hh, b_ih, b_hh,
      lin1_w, lin1_b, lin2_w, lin2_b, hidden, cell, out, ws, bar);
  (void)in_sizes; (void)n_in; (void)out_size; (void)ws_size;
}

// Round 3
// 49879.526 us; speedup vs baseline: 13.8569x; 1.8673x over previous
//
#include <hip/hip_runtime.h>
#include <math.h>

#define SD   2048   // sequence steps
#define HD   1024   // hidden size
#define TPB  1024   // 16 waves
#define NBLK 256    // one block per CU -> co-resident

// ---- ws layout (float offsets). First 4KB = barrier region. ----
#define E_OFF     1024
#define X_OFF     (E_OFF + SD)          // x == h1(prev step)
#define H0_OFF    (X_OFF + HD)
#define INP_OFF   (H0_OFF + HD)
#define CTXP_OFF  (INP_OFF + HD)        // fallback only: 16*HD
#define M_OFF     24576                 // 96KB-aligned; M is [1024][2048]
#define M_SZ      (HD * SD)
#define WS_NEED_M ((size_t)(M_OFF + M_SZ) * 4)

typedef unsigned long long u64;

// ---- coherent accessors (sc1, bypass L1/L2; no fences -> weights stay cached) ----
__device__ __forceinline__ float ldcf(const float* p) {
  return __hip_atomic_load(p, __ATOMIC_RELAXED, __HIP_MEMORY_SCOPE_AGENT);
}
__device__ __forceinline__ float2 ldc2(const float* p) {
  u64 u = __hip_atomic_load((const u64*)p, __ATOMIC_RELAXED, __HIP_MEMORY_SCOPE_AGENT);
  union { u64 u; float2 f; } c; c.u = u; return c.f;
}
__device__ __forceinline__ void stcf(float* p, float v) {
  __hip_atomic_store(p, v, __ATOMIC_RELAXED, __HIP_MEMORY_SCOPE_AGENT);
}
__device__ __forceinline__ unsigned ldb(const unsigned* p) {
  return __hip_atomic_load(p, __ATOMIC_RELAXED, __HIP_MEMORY_SCOPE_AGENT);
}
__device__ __forceinline__ void stb(unsigned* p, unsigned v) {
  __hip_atomic_store(p, v, __ATOMIC_RELAXED, __HIP_MEMORY_SCOPE_AGENT);
}

__device__ __forceinline__ float dot4(float4 a, float4 b) {
  return a.x * b.x + a.y * b.y + a.z * b.z + a.w * b.w;
}
__device__ __forceinline__ float wred(float v) {
  v += __shfl_xor(v, 32, 64); v += __shfl_xor(v, 16, 64);
  v += __shfl_xor(v, 8, 64);  v += __shfl_xor(v, 4, 64);
  v += __shfl_xor(v, 2, 64);  v += __shfl_xor(v, 1, 64);
  return v;
}
__device__ __forceinline__ float sigm(float x) { return 1.0f / (1.0f + __expf(-x)); }

// ---- flag barrier: per-block epoch flags (contention-free stores),
// master wave (block 0, wave 0) min-reduces 256 flags, broadcasts via 8 gens.
__device__ __forceinline__ void bar_arrive(unsigned* bar, unsigned ep) {
  __syncthreads();                       // drains vmcnt -> phase's sc1 stores visible
  if (threadIdx.x == 0) stb(bar + blockIdx.x, ep);
}
__device__ __forceinline__ void bar_wait(unsigned* bar, unsigned ep) {
  if (blockIdx.x == 0) {
    if (threadIdx.x < 64) {
      const int lane = threadIdx.x;
      for (;;) {
        unsigned a = ldb(bar + lane),        b = ldb(bar + 64 + lane);
        unsigned c = ldb(bar + 128 + lane),  d = ldb(bar + 192 + lane);
        unsigned m = a < b ? a : b, n = c < d ? c : d;
        m = m < n ? m : n;
#pragma unroll
        for (int s = 32; s; s >>= 1) {
          unsigned o = (unsigned)__shfl_xor((int)m, s, 64);
          m = m < o ? m : o;
        }
        if (m >= ep) break;
        __builtin_amdgcn_s_sleep(1);
      }
      if (lane < 8) stb(bar + 256 + lane * 16, ep);
    }
  } else if (threadIdx.x == 0) {
    while (ldb(bar + 256 + (blockIdx.x & 7) * 16) < ep)
      __builtin_amdgcn_s_sleep(1);
  }
  __syncthreads();
}
__device__ __forceinline__ void gridbar(unsigned* bar, unsigned ep) {
  bar_arrive(bar, ep); bar_wait(bar, ep);
}

// fused LSTM layer phase: gates = w_ih@in + w_hh@hprev + b; one gate-row per wave
__device__ __forceinline__ void lstm_phase(const float* __restrict__ w_ih_l,
                                           const float* __restrict__ w_hh_l,
                                           const float* __restrict__ b_ih_l,
                                           const float* __restrict__ b_hh_l,
                                           const float* lds_in, const float* lds_hprev,
                                           float* lds_g, float* lds_c,
                                           float* ws_out, int bid, int wid, int lane, int tid) {
  {
    const int k = bid * 4 + (wid >> 2), g = wid & 3;
    const float* wi = w_ih_l + (size_t)(g * HD + k) * HD;
    const float* wh = w_hh_l + (size_t)(g * HD + k) * HD;
    float acc = 0.f;
#pragma unroll
    for (int it = 0; it < 4; ++it) {
      acc += dot4(*(const float4*)(wi + it * 256 + lane * 4),
                  *(const float4*)(lds_in + it * 256 + lane * 4));
      acc += dot4(*(const float4*)(wh + it * 256 + lane * 4),
                  *(const float4*)(lds_hprev + it * 256 + lane * 4));
    }
    acc = wred(acc);
    if (lane == 0) lds_g[wid] = acc;
  }
  __syncthreads();
  if (tid < 4) {
    const int k = bid * 4 + tid;
    float gi = lds_g[tid * 4 + 0] + b_ih_l[k]          + b_hh_l[k];
    float gf = lds_g[tid * 4 + 1] + b_ih_l[HD + k]     + b_hh_l[HD + k];
    float gg = lds_g[tid * 4 + 2] + b_ih_l[2 * HD + k] + b_hh_l[2 * HD + k];
    float go = lds_g[tid * 4 + 3] + b_ih_l[3 * HD + k] + b_hh_l[3 * HD + k];
    float c = sigm(gf) * lds_c[tid] + sigm(gi) * tanhf(gg);
    lds_c[tid] = c;
    stcf(ws_out + k, sigm(go) * tanhf(c));
  }
}

__device__ void classifier_block(const float* lds_xv, const float* __restrict__ lin1_w,
                                 const float* __restrict__ lin1_b,
                                 const float* __restrict__ lin2_w,
                                 const float* __restrict__ lin2_b,
                                 float* __restrict__ out2, float* lds_cls) {
  const int tid = threadIdx.x, wid = tid >> 6, lane = tid & 63;
#pragma unroll
  for (int oi = 0; oi < 4; ++oi) {
    const int o = wid * 4 + oi;
    float acc = 0.f;
#pragma unroll
    for (int it = 0; it < 4; ++it)
      acc += dot4(*(const float4*)(lin1_w + (size_t)o * HD + it * 256 + lane * 4),
                  *(const float4*)(lds_xv + it * 256 + lane * 4));
    acc = wred(acc);
    if (lane == 0) lds_cls[o] = fmaxf(acc + lin1_b[o], 0.f);
  }
  __syncthreads();
  if (tid == 0) {
    float l0 = lin2_b[0], l1 = lin2_b[1];
#pragma unroll
    for (int j = 0; j < 64; ++j) {
      l0 += lin2_w[j] * lds_cls[j];
      l1 += lin2_w[64 + j] * lds_cls[j];
    }
    float m = fmaxf(l0, l1);
    float e0 = __expf(l0 - m), e1 = __expf(l1 - m);
    float inv = 1.f / (e0 + e1);
    out2[0] = e0 * inv; out2[1] = e1 * inv;
  }
  __syncthreads();
}

template <int USE_M>
__global__ void __launch_bounds__(TPB, 4)
decoder_kernel(const float* __restrict__ enc, const float* __restrict__ attn_w,
               const float* __restrict__ attn_b, const float* __restrict__ comb_w,
               const float* __restrict__ comb_b, const float* __restrict__ w_ih,
               const float* __restrict__ w_hh, const float* __restrict__ b_ih,
               const float* __restrict__ b_hh, const float* __restrict__ lin1_w,
               const float* __restrict__ lin1_b, const float* __restrict__ lin2_w,
               const float* __restrict__ lin2_b, const float* __restrict__ hidden,
               const float* __restrict__ cell, float* __restrict__ out,
               float* __restrict__ ws) {
  __shared__ __align__(16) float lds_x[HD];
  __shared__ __align__(16) float lds_h0[HD];
  __shared__ __align__(16) float lds_v[HD];      // inp (C) / h0' (D) / ctx (fallback)
  __shared__ __align__(16) float lds_e[SD];
  __shared__ __align__(16) float lds_enc[8 * HD];  // prologue stage / fallback scratch
  __shared__ float lds_p[64], lds_g[64], lds_cls[64];
  __shared__ float lds_c0[4], lds_c1[4], lds_sum[1];

  const int tid = threadIdx.x, wid = tid >> 6, lane = tid & 63;
  const int bid = blockIdx.x;
  unsigned* bar = (unsigned*)ws;
  unsigned ep = 0;

  // ================= prologue =================
  if (USE_M) {
    // M[j,i] = comb_w[j,1024:] . enc[i,:]  (j-tile 32, i-tile 256 per block)
    const int j0 = (bid >> 3) * 32, i0 = (bid & 7) * 256;
    const int jA = j0 + wid * 2, jB = jA + 1;
    float4 cA[4], cB[4];
#pragma unroll
    for (int it = 0; it < 4; ++it) {
      cA[it] = *(const float4*)(comb_w + (size_t)jA * 2048 + 1024 + it * 256 + lane * 4);
      cB[it] = *(const float4*)(comb_w + (size_t)jB * 2048 + 1024 + it * 256 + lane * 4);
    }
    for (int ib = 0; ib < 32; ++ib) {
      const int rl = tid >> 7, c8 = (tid & 127) * 8;
      const float* src = enc + (size_t)(i0 + ib * 8 + rl) * HD + c8;
      *(float4*)(lds_enc + rl * HD + c8)     = *(const float4*)src;
      *(float4*)(lds_enc + rl * HD + c8 + 4) = *(const float4*)(src + 4);
      __syncthreads();
      for (int ii = 0; ii < 8; ++ii) {
        float aA = 0.f, aB = 0.f;
#pragma unroll
        for (int it = 0; it < 4; ++it) {
          float4 e4 = *(const float4*)(lds_enc + ii * HD + it * 256 + lane * 4);
          aA += dot4(cA[it], e4); aB += dot4(cB[it], e4);
        }
        aA = wred(aA); aB = wred(aB);
        if (lane == 0) {
          const int i = i0 + ib * 8 + ii;
          stcf(ws + M_OFF + (size_t)jA * SD + i, aA);
          stcf(ws + M_OFF + (size_t)jB * SD + i, aB);
        }
      }
      __syncthreads();
    }
  }
  if (bid == 0) {
    for (int i = tid; i < HD; i += TPB) {
      stcf(ws + H0_OFF + i, hidden[i]);
      stcf(ws + X_OFF + i, 0.f);
    }
  }
  if (tid < 4) { lds_c0[tid] = cell[bid * 4 + tid]; lds_c1[tid] = cell[HD + bid * 4 + tid]; }
  gridbar(bar, ++ep);

  // ================= main loop =================
  for (int t = 0; t < SD; ++t) {
    // ---- Phase A: stage x,h0; scores e = exp(attn_w@[x;h0]+b) ----
    if (tid < 512) { *(float2*)(lds_x + tid * 2) = ldc2(ws + X_OFF + tid * 2); }
    else { const int q = tid - 512; *(float2*)(lds_h0 + q * 2) = ldc2(ws + H0_OFF + q * 2); }
    __syncthreads();
    {
      const int r = bid * 8 + (wid >> 1), half = wid & 1;
      const float* vec = half ? lds_h0 : lds_x;
      const float* wr = attn_w + (size_t)r * 2048 + half * 1024;
      float acc = 0.f;
#pragma unroll
      for (int it = 0; it < 4; ++it)
        acc += dot4(*(const float4*)(wr + it * 256 + lane * 4),
                    *(const float4*)(vec + it * 256 + lane * 4));
      acc = wred(acc);
      if (lane == 0) lds_p[wid] = acc;
    }
    __syncthreads();
    if (tid < 8) {
      float v = lds_p[2 * tid] + lds_p[2 * tid + 1] + attn_b[bid * 8 + tid];
      stcf(ws + E_OFF + bid * 8 + tid, __expf(v));
    }
    bar_arrive(bar, ++ep);
    if (bid == NBLK - 1 && t > 0)                      // inside barrier window
      classifier_block(lds_x, lin1_w, lin1_b, lin2_w, lin2_b,
                       out + (size_t)(t - 1) * 2, lds_cls);
    bar_wait(bar, ep);

    // ---- Phase B: inp = relu(Wx@x + (M@e)/sum + b) ----
    { float2 e2 = ldc2(ws + E_OFF + tid * 2); *(float2*)(lds_e + tid * 2) = e2; }
    __syncthreads();
    float invs;
    {
      float s = 0.f;
#pragma unroll
      for (int it = 0; it < 8; ++it) {
        float4 e4 = *(const float4*)(lds_e + it * 256 + lane * 4);
        s += e4.x + e4.y + e4.z + e4.w;
      }
      invs = 1.f / wred(s);
    }
    if (USE_M) {
      {
        const int j = bid * 4 + (wid >> 2), p = wid & 3;
        float4 wx = *(const float4*)(comb_w + (size_t)j * 2048 + p * 256 + lane * 4);
        float4 x4 = *(const float4*)(lds_x + p * 256 + lane * 4);
        float ax = dot4(wx, x4);
        float am = 0.f;
#pragma unroll
        for (int it = 0; it < 2; ++it) {
          float4 m4 = *(const float4*)(ws + M_OFF + (size_t)j * SD + p * 512 + it * 256 + lane * 4);
          float4 e4 = *(const float4*)(lds_e + p * 512 + it * 256 + lane * 4);
          am += dot4(m4, e4);
        }
        float acc = wred(ax + invs * am);
        if (lane == 0) lds_p[wid] = acc;
      }
      __syncthreads();
      if (tid < 4) {
        const int j = bid * 4 + tid;
        float v = lds_p[tid * 4] + lds_p[tid * 4 + 1] + lds_p[tid * 4 + 2] + lds_p[tid * 4 + 3]
                  + comb_b[j];
        stcf(ws + INP_OFF + j, fmaxf(v, 0.f));
      }
      gridbar(bar, ++ep);
    } else {
      // fallback B1: ctx partials (16 chunks x 16 col-slices)
      if (wid == 0 && lane == 0) lds_sum[0] = invs;
      {
        const int chunk = bid >> 4, hg = bid & 15;
        const int i0 = chunk * 128 + wid * 8, hb = hg * 64 + lane;
        float a = 0.f;
#pragma unroll
        for (int ii = 0; ii < 8; ++ii)
          a += lds_e[i0 + ii] * enc[(size_t)(i0 + ii) * HD + hb];
        lds_enc[wid * 64 + lane] = a;
      }
      __syncthreads();
      if (wid == 0) {
        const int chunk = bid >> 4, hg = bid & 15, hb = hg * 64 + lane;
        float s = 0.f;
#pragma unroll
        for (int w2 = 0; w2 < 16; ++w2) s += lds_enc[w2 * 64 + lane];
        stcf(ws + CTXP_OFF + chunk * HD + hb, s);
      }
      gridbar(bar, ++ep);
      // fallback B2: reduce ctx, inp rows
      const float invs2 = lds_sum[0];
      if (tid < 512) {
        float sx = 0.f, sy = 0.f;
#pragma unroll
        for (int ch = 0; ch < 16; ++ch) {
          float2 p2 = ldc2(ws + CTXP_OFF + ch * HD + tid * 2);
          sx += p2.x; sy += p2.y;
        }
        lds_v[tid * 2] = sx * invs2; lds_v[tid * 2 + 1] = sy * invs2;
      }
      __syncthreads();
      {
        const int j = bid * 4 + (wid >> 2), p = wid & 3;
        const float* vec = (p < 2) ? (lds_x + p * 512) : (lds_v + (p - 2) * 512);
        float acc = 0.f;
#pragma unroll
        for (int it = 0; it < 2; ++it)
          acc += dot4(*(const float4*)(comb_w + (size_t)j * 2048 + p * 512 + it * 256 + lane * 4),
                      *(const float4*)(vec + it * 256 + lane * 4));
        acc = wred(acc);
        if (lane == 0) lds_p[wid] = acc;
      }
      __syncthreads();
      if (tid < 4) {
        const int j = bid * 4 + tid;
        float v = lds_p[tid * 4] + lds_p[tid * 4 + 1] + lds_p[tid * 4 + 2] + lds_p[tid * 4 + 3]
                  + comb_b[j];
        stcf(ws + INP_OFF + j, fmaxf(v, 0.f));
      }
      gridbar(bar, ++ep);
    }

    // ---- Phase C: LSTM layer 0 (fused w_ih|w_hh, h_prev = lds_h0) ----
    if (tid < 512) *(float2*)(lds_v + tid * 2) = ldc2(ws + INP_OFF + tid * 2);
    __syncthreads();
    lstm_phase(w_ih, w_hh, b_ih, b_hh, lds_v, lds_h0, lds_g, lds_c0,
               ws + H0_OFF, bid, wid, lane, tid);
    gridbar(bar, ++ep);

    // ---- Phase D: LSTM layer 1 (h_prev = lds_x == h1(t-1)) ----
    if (t == 0) {
      if (tid < 512) *(float2*)(lds_x + tid * 2) = *(const float2*)(hidden + HD + tid * 2);
    }
    if (tid < 512) *(float2*)(lds_v + tid * 2) = ldc2(ws + H0_OFF + tid * 2);
    __syncthreads();
    lstm_phase(w_ih + (size_t)4 * HD * HD, w_hh + (size_t)4 * HD * HD,
               b_ih + 4 * HD, b_hh + 4 * HD, lds_v, lds_x, lds_g, lds_c1,
               ws + X_OFF, bid, wid, lane, tid);
    gridbar(bar, ++ep);
  }

  // ================= epilogue =================
  if (tid < 4) {
    out[4096 + 2 * HD + bid * 4 + tid] = lds_c0[tid];
    out[4096 + 3 * HD + bid * 4 + tid] = lds_c1[tid];
  }
  if (bid == 0 && tid < HD) {
    out[4096 + tid]      = ldcf(ws + H0_OFF + tid);
    out[4096 + HD + tid] = ldcf(ws + X_OFF + tid);
  }
  if (bid == NBLK - 1) {
    if (tid < 512) *(float2*)(lds_x + tid * 2) = ldc2(ws + X_OFF + tid * 2);
    __syncthreads();
    classifier_block(lds_x, lin1_w, lin1_b, lin2_w, lin2_b,
                     out + (size_t)(SD - 1) * 2, lds_cls);
  }
}

extern "C" void kernel_launch(void* const* d_in, const int* in_sizes, int n_in,
                              void* d_out, int out_size, void* d_ws, size_t ws_size,
                              hipStream_t stream) {
  const float* enc    = (const float*)d_in[0];
  const float* hidden = (const float*)d_in[1];
  const float* cell   = (const float*)d_in[2];
  const float* attn_w = (const float*)d_in[3];
  const float* attn_b = (const float*)d_in[4];
  const float* comb_w = (const float*)d_in[5];
  const float* comb_b = (const float*)d_in[6];
  const float* w_ih   = (const float*)d_in[7];
  const float* w_hh   = (const float*)d_in[8];
  const float* b_ih   = (const float*)d_in[9];
  const float* b_hh   = (const float*)d_in[10];
  const float* lin1_w = (const float*)d_in[11];
  const float* lin1_b = (const float*)d_in[12];
  const float* lin2_w = (const float*)d_in[13];
  const float* lin2_b = (const float*)d_in[14];
  float* out = (float*)d_out;
  float* ws  = (float*)d_ws;

  hipMemsetAsync(d_ws, 0, 4096, stream);   // barrier flags/gens
  if (ws_size >= WS_NEED_M) {
    decoder_kernel<1><<<dim3(NBLK), dim3(TPB), 0, stream>>>(
        enc, attn_w, attn_b, comb_w, comb_b, w_ih, w_hh, b_ih, b_hh,
        lin1_w, lin1_b, lin2_w, lin2_b, hidden, cell, out, ws);
  } else {
    decoder_kernel<0><<<dim3(NBLK), dim3(TPB), 0, stream>>>(
        enc, attn_w, attn_b, comb_w, comb_b, w_ih, w_hh, b_ih, b_hh,
        lin1_w, lin1_b, lin2_w, lin2_b, hidden, cell, out, ws);
  }
  (void)in_sizes; (void)n_in; (void)out_size;
}